// Round 2
// baseline (335.668 us; speedup 1.0000x reference)
//
#include <hip/hip_runtime.h>

// Geometry: G=256 graphs x 64 nodes, H=8 heads x D=8, IN_DIM=EDGE_DIM=64
// EF = 1048576 full edges, ES = 262144 sparse edges.
// edge f = b*4096 + i*64 + j (src=i, dst=j); sparse s = b*1024 + j*16 + k, i=(j+1+k)&63.
//
// attn grid: 512 blocks = (graph b, j-half). 512 threads.
//   P0 thread = (lane=node row, wave=8 output cols)   -> Q(32 rows),K,V in LDS
//   P2 thread = one sparse-edge row (512 rows/block)  -> proj_e in LDS
//   P3 thread = (j_local 0..31, hh 0..7, half 0..1), 32 i-iterations, shfl reduce
//   P5 thread = (row_local = t>>4, colquad = t&15)    -> h_out
// LDS tiles [R][64] use XOR swizzle: elem(r,c) at r*64 + (((c>>3)^(r&7))<<3) + (c&7).

__global__ __launch_bounds__(512, 4) void attn_kernel(
    const float* __restrict__ h,
    const float* __restrict__ e,
    const float* __restrict__ adj2,
    const float* __restrict__ rel,
    const float* __restrict__ Wq, const float* __restrict__ bq,
    const float* __restrict__ Wk, const float* __restrict__ bk,
    const float* __restrict__ Wv, const float* __restrict__ bv,
    const float* __restrict__ Wpe, const float* __restrict__ bpe,
    const float* __restrict__ Wo, const float* __restrict__ bo,
    float* __restrict__ h_out,
    float* __restrict__ scsp, int sstride)
{
    __shared__ float shK[64 * 64];   // 16 KB swizzled
    __shared__ float shV[64 * 64];   // 16 KB swizzled
    __shared__ float shQ[32 * 64];   // 8 KB swizzled (this block's j rows; reused for wV)
    __shared__ float shPE[512 * 8];  // 16 KB
    __shared__ float shSC[512 * 8];  // 16 KB (sc_sp staging for coalesced dump)

    const int b2   = blockIdx.x;
    const int b    = b2 >> 1;
    const int joff = (b2 & 1) << 5;          // 0 or 32
    const int t    = threadIdx.x;
    const int lane = t & 63;
    const int wu   = __builtin_amdgcn_readfirstlane(t >> 6);  // wave id, uniform

    // ---- P0: Q,K,V = h @ W^T + b for all 64 rows of graph b
    {
        const float* hrow = h + (size_t)(b * 64 + lane) * 64;
        float accQ[8], accK[8], accV[8];
        #pragma unroll
        for (int cc = 0; cc < 8; ++cc) {
            const int c = wu * 8 + cc;
            accQ[cc] = bq[c]; accK[cc] = bk[c]; accV[cc] = bv[c];
        }
        #pragma unroll
        for (int k0 = 0; k0 < 4; ++k0) {
            float hv[16];
            #pragma unroll
            for (int u = 0; u < 4; ++u) {
                const float4 x = ((const float4*)hrow)[k0 * 4 + u];
                hv[u*4+0] = x.x; hv[u*4+1] = x.y; hv[u*4+2] = x.z; hv[u*4+3] = x.w;
            }
            #pragma unroll
            for (int cc = 0; cc < 8; ++cc) {
                const int c = wu * 8 + cc;
                const float* wq  = Wq + c * 64 + k0 * 16;   // wave-uniform -> s_load
                const float* wk  = Wk + c * 64 + k0 * 16;
                const float* wvp = Wv + c * 64 + k0 * 16;
                #pragma unroll
                for (int k = 0; k < 16; ++k) {
                    accQ[cc] = fmaf(hv[k], wq[k],  accQ[cc]);
                    accK[cc] = fmaf(hv[k], wk[k],  accK[cc]);
                    accV[cc] = fmaf(hv[k], wvp[k], accV[cc]);
                }
            }
        }
        const int go = ((wu ^ (lane & 7)) << 3);  // swizzled col-group offset
        float* kp = &shK[lane * 64 + go];
        *(float4*)(kp)     = make_float4(accK[0], accK[1], accK[2], accK[3]);
        *(float4*)(kp + 4) = make_float4(accK[4], accK[5], accK[6], accK[7]);
        float* vp = &shV[lane * 64 + go];
        *(float4*)(vp)     = make_float4(accV[0], accV[1], accV[2], accV[3]);
        *(float4*)(vp + 4) = make_float4(accV[4], accV[5], accV[6], accV[7]);
        if (lane >= joff && lane < joff + 32) {
            const int rl = lane - joff;
            float* qp = &shQ[rl * 64 + ((wu ^ (rl & 7)) << 3)];
            *(float4*)(qp)     = make_float4(accQ[0], accQ[1], accQ[2], accQ[3]);
            *(float4*)(qp + 4) = make_float4(accQ[4], accQ[5], accQ[6], accQ[7]);
        }
    }
    __syncthreads();

    // ---- P1: per-thread Q fragment. thread = (j_local, hh, half)
    const int j_local = t >> 4;
    const int hh      = (t >> 1) & 7;
    const int half    = t & 1;
    const int j       = joff + j_local;
    float q[8];
    {
        const float* qp = &shQ[j_local * 64 + ((hh ^ (j_local & 7)) << 3)];
        const float4 a = *(const float4*)qp;
        const float4 c = *(const float4*)(qp + 4);
        q[0]=a.x; q[1]=a.y; q[2]=a.z; q[3]=a.w;
        q[4]=c.x; q[5]=c.y; q[6]=c.z; q[7]=c.w;
    }

    // ---- P2: proj_e for this block's 512 sparse rows (one per thread)
    {
        const float* erow = e + ((size_t)b * 1024 + joff * 16 + t) * 64;
        float acc[8];
        #pragma unroll
        for (int h2 = 0; h2 < 8; ++h2) acc[h2] = bpe[h2];
        #pragma unroll
        for (int k0 = 0; k0 < 4; ++k0) {
            float ev[16];
            #pragma unroll
            for (int u = 0; u < 4; ++u) {
                const float4 x = ((const float4*)erow)[k0 * 4 + u];
                ev[u*4+0] = x.x; ev[u*4+1] = x.y; ev[u*4+2] = x.z; ev[u*4+3] = x.w;
            }
            #pragma unroll
            for (int h2 = 0; h2 < 8; ++h2) {
                const float* wp = Wpe + h2 * 64 + k0 * 16;  // block-uniform -> s_load
                #pragma unroll
                for (int k = 0; k < 16; ++k)
                    acc[h2] = fmaf(ev[k], wp[k], acc[h2]);
            }
        }
        float* p0 = &shPE[t * 8];
        *(float4*)(p0)     = make_float4(acc[0], acc[1], acc[2], acc[3]);
        *(float4*)(p0 + 4) = make_float4(acc[4], acc[5], acc[6], acc[7]);
    }
    __syncthreads();

    // ---- P3: scores + softmax accumulation over this thread's 32 i's
    float den = 0.f;
    float wv[8] = {0.f,0.f,0.f,0.f,0.f,0.f,0.f,0.f};
    const float* adjB = adj2 + (size_t)b * 4096;
    const float* relB = rel  + (size_t)b * 4096 * 8;
    const float inv_scale = 0.35355339059327379f;  // 1/sqrt(8)
    #pragma unroll 4
    for (int it = 0; it < 32; ++it) {
        const int i  = (half << 5) + it;
        const int kb = i * 64 + ((hh ^ (i & 7)) << 3);
        const float4 kA = *(const float4*)&shK[kb];
        const float4 kB = *(const float4*)&shK[kb + 4];
        float s;
        s = kA.x * q[0];
        s = fmaf(kA.y, q[1], s); s = fmaf(kA.z, q[2], s); s = fmaf(kA.w, q[3], s);
        s = fmaf(kB.x, q[4], s); s = fmaf(kB.y, q[5], s); s = fmaf(kB.z, q[6], s);
        s = fmaf(kB.w, q[7], s);
        const int eidx = i * 64 + j;
        const float a2 = adjB[eidx];
        const float rp = relB[eidx * 8 + hh];
        s = fmaf(s * inv_scale, a2, rp);          // score (pre proj_e, unclipped)
        const int kidx = (i - j - 1) & 63;
        if (kidx < 16) {                          // sparse edge (i -> j)
            const int sl = j_local * 16 + kidx;
            shSC[sl * 8 + hh] = s;                // sc_sp for e_out kernel
            s += shPE[sl * 8 + hh];               // softmax sees sc_sp + proj_e
        }
        s = fminf(fmaxf(s, -5.f), 5.f);
        const float ex = __expf(s);
        den += ex;
        const float4 vA = *(const float4*)&shV[kb];
        const float4 vB = *(const float4*)&shV[kb + 4];
        wv[0] = fmaf(ex, vA.x, wv[0]); wv[1] = fmaf(ex, vA.y, wv[1]);
        wv[2] = fmaf(ex, vA.z, wv[2]); wv[3] = fmaf(ex, vA.w, wv[3]);
        wv[4] = fmaf(ex, vB.x, wv[4]); wv[5] = fmaf(ex, vB.y, wv[5]);
        wv[6] = fmaf(ex, vB.z, wv[6]); wv[7] = fmaf(ex, vB.w, wv[7]);
    }
    // reduce the two i-halves (lane pair differs in bit 0)
    den += __shfl_xor(den, 1);
    #pragma unroll
    for (int u = 0; u < 8; ++u) wv[u] += __shfl_xor(wv[u], 1);
    if (half == 0) {
        const float id = 1.f / den;
        float* wp = &shQ[j_local * 64 + ((hh ^ (j_local & 7)) << 3)];  // shQ := wV
        *(float4*)(wp)     = make_float4(wv[0]*id, wv[1]*id, wv[2]*id, wv[3]*id);
        *(float4*)(wp + 4) = make_float4(wv[4]*id, wv[5]*id, wv[6]*id, wv[7]*id);
    }
    __syncthreads();

    // ---- P4: coalesced sc_sp dump (thread t -> sparse row t of this block)
    {
        const float4 a = *(const float4*)&shSC[t * 8];
        const float4 c = *(const float4*)&shSC[t * 8 + 4];
        float* sp = scsp + (size_t)((size_t)b * 1024 + joff * 16 + t) * sstride;
        *(float4*)(sp)     = a;
        *(float4*)(sp + 4) = c;
    }

    // ---- P5: h_out rows = this block's 32 j's. thread = (rl = t>>4, cq = t&15)
    {
        const int rl = t >> 4;
        const int cq = t & 15;
        float acc[4];
        #pragma unroll
        for (int u = 0; u < 4; ++u) acc[u] = bo[cq * 4 + u];
        #pragma unroll
        for (int k0 = 0; k0 < 4; ++k0) {
            float tv[16];
            #pragma unroll
            for (int u = 0; u < 4; ++u) {
                const int c = k0 * 16 + u * 4;
                const float* p = &shQ[rl * 64 + (((c >> 3) ^ (rl & 7)) << 3) + (c & 7)];
                const float4 x = *(const float4*)p;
                tv[u*4+0] = x.x; tv[u*4+1] = x.y; tv[u*4+2] = x.z; tv[u*4+3] = x.w;
            }
            #pragma unroll
            for (int u = 0; u < 4; ++u) {
                const float* wo = Wo + (cq * 4 + u) * 64 + k0 * 16;
                #pragma unroll
                for (int k = 0; k < 16; ++k)
                    acc[u] = fmaf(tv[k], wo[k], acc[u]);
            }
        }
        float* orow = h_out + (size_t)(b * 64 + joff + rl) * 64 + cq * 4;
        *(float4*)orow = make_float4(acc[0], acc[1], acc[2], acc[3]);
    }
}

// e_out = (sc_sp @ Wap^T + bap + e) @ Woe^T + boe.  One thread per edge row.
__global__ __launch_bounds__(256, 4) void eout_kernel(
    const float* __restrict__ e,
    const float* __restrict__ scsp,
    const float* __restrict__ Wap, const float* __restrict__ bap,
    const float* __restrict__ Woe, const float* __restrict__ boe,
    float* __restrict__ e_out, int sstride)
{
    const int row = blockIdx.x * 256 + threadIdx.x;    // 0..ES-1
    const float* erow = e + (size_t)row * 64;

    float trow[64];
    #pragma unroll
    for (int v = 0; v < 16; ++v) {
        const float4 x = ((const float4*)erow)[v];
        trow[v*4+0] = x.x; trow[v*4+1] = x.y; trow[v*4+2] = x.z; trow[v*4+3] = x.w;
    }
    float sc[8];
    {
        const float* srow = scsp + (size_t)row * sstride;
        const float4 a = *(const float4*)srow;
        const float4 c = *(const float4*)(srow + 4);
        sc[0]=a.x; sc[1]=a.y; sc[2]=a.z; sc[3]=a.w;
        sc[4]=c.x; sc[5]=c.y; sc[6]=c.z; sc[7]=c.w;
    }
    // t = e + bap + sc_sp @ Wap^T
    #pragma unroll
    for (int c = 0; c < 64; ++c) {
        float acc = trow[c] + bap[c];
        #pragma unroll
        for (int h2 = 0; h2 < 8; ++h2)
            acc = fmaf(sc[h2], Wap[c * 8 + h2], acc);   // uniform -> s_load
        trow[c] = acc;
    }
    // e_out = t @ Woe^T + boe, 16 output cols at a time
    float* orow = e_out + (size_t)row * 64;
    for (int cc4 = 0; cc4 < 4; ++cc4) {                 // runtime loop: code size
        float acc[16];
        #pragma unroll
        for (int u = 0; u < 16; ++u) acc[u] = boe[cc4 * 16 + u];
        #pragma unroll
        for (int u = 0; u < 16; ++u) {
            const float* wr = Woe + (cc4 * 16 + u) * 64;  // uniform row base
            #pragma unroll
            for (int k = 0; k < 64; ++k)
                acc[u] = fmaf(trow[k], wr[k], acc[u]);
        }
        #pragma unroll
        for (int u = 0; u < 4; ++u)
            *(float4*)&orow[cc4 * 16 + u * 4] =
                make_float4(acc[u*4+0], acc[u*4+1], acc[u*4+2], acc[u*4+3]);
    }
}

extern "C" void kernel_launch(void* const* d_in, const int* in_sizes, int n_in,
                              void* d_out, int out_size, void* d_ws, size_t ws_size,
                              hipStream_t stream) {
    const float* h    = (const float*)d_in[0];
    const float* e    = (const float*)d_in[1];
    const float* adj2 = (const float*)d_in[2];
    const float* rel  = (const float*)d_in[3];
    const float* Wq   = (const float*)d_in[4];  const float* bq  = (const float*)d_in[5];
    const float* Wk   = (const float*)d_in[6];  const float* bk  = (const float*)d_in[7];
    const float* Wv   = (const float*)d_in[8];  const float* bv  = (const float*)d_in[9];
    const float* Wpe  = (const float*)d_in[10]; const float* bpe = (const float*)d_in[11];
    const float* Wap  = (const float*)d_in[12]; const float* bap = (const float*)d_in[13];
    const float* Wo   = (const float*)d_in[14]; const float* bo  = (const float*)d_in[15];
    const float* Woe  = (const float*)d_in[16]; const float* boe = (const float*)d_in[17];

    float* out  = (float*)d_out;
    float* hout = out;                    // [16384*64]
    float* eout = out + 16384 * 64;       // [262144*64]

    // sc_sp staging: compact [ES][8] in d_ws if it fits, else stride-64 inside e_out
    const size_t need = (size_t)262144 * 8 * sizeof(float);   // 8 MB
    const int sstride = (ws_size >= need) ? 8 : 64;
    float* scsp = (sstride == 8) ? (float*)d_ws : eout;

    attn_kernel<<<dim3(512), dim3(512), 0, stream>>>(
        h, e, adj2, rel, Wq, bq, Wk, bk, Wv, bv, Wpe, bpe, Wo, bo, hout, scsp, sstride);
    eout_kernel<<<dim3(1024), dim3(256), 0, stream>>>(
        e, scsp, Wap, bap, Woe, boe, eout, sstride);
}

// Round 3
// 276.895 us; speedup vs baseline: 1.2123x; 1.2123x over previous
//
#include <hip/hip_runtime.h>

// Geometry: G=256 graphs x 64 nodes, H=8 heads x D=8, IN_DIM=EDGE_DIM=64
// EF = 1048576 full edges, ES = 262144 sparse edges.
// edge f = b*4096 + i*64 + j (src=i, dst=j); sparse s = b*1024 + j*16 + k, i=(j+1+k)&63.

// ---- attn prefetch macros (textual, all array indices static after unroll)
#define LOADCH(Ab, Rb, ch) { _Pragma("unroll") \
  for (int u_ = 0; u_ < 8; ++u_) { const int ii_ = (half << 5) + (ch) * 8 + u_; \
    Ab[u_] = adjP[(size_t)ii_ * 64]; Rb[u_] = relP[(size_t)ii_ * 512]; } }

#define COMPCH(Ab, Rb, ch) { _Pragma("unroll") \
  for (int u_ = 0; u_ < 8; ++u_) { \
    const int i_ = (half << 5) + (ch) * 8 + u_; \
    const int kb_ = i_ * 64 + ((hh ^ (i_ & 7)) << 3); \
    const float4 kA = *(const float4*)&shK[kb_]; \
    const float4 kB = *(const float4*)&shK[kb_ + 4]; \
    float s_ = kA.x * q[0]; \
    s_ = fmaf(kA.y, q[1], s_); s_ = fmaf(kA.z, q[2], s_); s_ = fmaf(kA.w, q[3], s_); \
    s_ = fmaf(kB.x, q[4], s_); s_ = fmaf(kB.y, q[5], s_); s_ = fmaf(kB.z, q[6], s_); \
    s_ = fmaf(kB.w, q[7], s_); \
    s_ = fmaf(s_ * inv_scale, Ab[u_], Rb[u_]); \
    const int kidx_ = (i_ - j - 1) & 63; \
    if (kidx_ < 16) { const int sl_ = j_local * 16 + kidx_; \
      shSC[sl_ * 8 + hh] = s_; s_ += shPE[sl_ * 8 + hh]; } \
    s_ = fminf(fmaxf(s_, -5.f), 5.f); \
    const float ex_ = __expf(s_); den += ex_; \
    const float4 vA = *(const float4*)&shV[kb_]; \
    const float4 vB = *(const float4*)&shV[kb_ + 4]; \
    wv[0] = fmaf(ex_, vA.x, wv[0]); wv[1] = fmaf(ex_, vA.y, wv[1]); \
    wv[2] = fmaf(ex_, vA.z, wv[2]); wv[3] = fmaf(ex_, vA.w, wv[3]); \
    wv[4] = fmaf(ex_, vB.x, wv[4]); wv[5] = fmaf(ex_, vB.y, wv[5]); \
    wv[6] = fmaf(ex_, vB.z, wv[6]); wv[7] = fmaf(ex_, vB.w, wv[7]); } }

#define ELOAD(Eb, k0) { _Pragma("unroll") for (int v_ = 0; v_ < 4; ++v_) { \
  const float4 x_ = ((const float4*)erow)[(k0) * 4 + v_]; \
  Eb[v_*4+0] = x_.x; Eb[v_*4+1] = x_.y; Eb[v_*4+2] = x_.z; Eb[v_*4+3] = x_.w; } }

#define ECONS(Eb, k0) { _Pragma("unroll") for (int h2_ = 0; h2_ < 8; ++h2_) { \
  const float* wp_ = Wpe + h2_ * 64 + (k0) * 16; \
  _Pragma("unroll") for (int k_ = 0; k_ < 16; ++k_) \
    pe[h2_] = fmaf(Eb[k_], wp_[k_], pe[h2_]); } }

__global__ __launch_bounds__(512, 4) void attn_kernel(
    const float* __restrict__ h,
    const float* __restrict__ e,
    const float* __restrict__ adj2,
    const float* __restrict__ rel,
    const float* __restrict__ Wq, const float* __restrict__ bq,
    const float* __restrict__ Wk, const float* __restrict__ bk,
    const float* __restrict__ Wv, const float* __restrict__ bv,
    const float* __restrict__ Wpe, const float* __restrict__ bpe,
    const float* __restrict__ Wo, const float* __restrict__ bo,
    float* __restrict__ h_out,
    float* __restrict__ scsp, int sstride)
{
    __shared__ float shK[64 * 64];   // swizzled [r][c] at r*64 + (((c>>3)^(r&7))<<3)+(c&7)
    __shared__ float shV[64 * 64];
    __shared__ float shQ[32 * 64];   // this block's j rows; reused for wV
    __shared__ float shPE[512 * 8];
    __shared__ float shSC[512 * 8];

    const int b2   = blockIdx.x;
    const int b    = b2 >> 1;
    const int joff = (b2 & 1) << 5;          // 0 or 32
    const int t    = threadIdx.x;
    const int lane = t & 63;
    const int wu   = __builtin_amdgcn_readfirstlane(t >> 6);

    // P3 thread mapping (computed up front for prefetch addressing)
    const int j_local = t >> 4;
    const int hh      = (t >> 1) & 7;
    const int half    = t & 1;
    const int j       = joff + j_local;

    const float* erow = e + ((size_t)b * 1024 + joff * 16 + t) * 64;   // P2 row = t
    const float* adjP = adj2 + (size_t)b * 4096 + j;
    const float* relP = rel  + (size_t)b * 4096 * 8 + j * 8 + hh;

    float E0[16], E1[16], A0[8], R0[8], A1[8], R1[8];
    ELOAD(E0, 0);          // proj_e chunk 0: covered by P0 compute
    LOADCH(A0, R0, 0);     // adj/rel chunk 0: covered by P0 compute

    // ---- P0: Q,K,V = h @ W^T + b for all 64 rows of graph b
    {
        const float* hrow = h + (size_t)(b * 64 + lane) * 64;
        float accQ[8], accK[8], accV[8];
        #pragma unroll
        for (int cc = 0; cc < 8; ++cc) {
            const int c = wu * 8 + cc;
            accQ[cc] = bq[c]; accK[cc] = bk[c]; accV[cc] = bv[c];
        }
        #pragma unroll
        for (int k0 = 0; k0 < 4; ++k0) {
            float hv[16];
            #pragma unroll
            for (int u = 0; u < 4; ++u) {
                const float4 x = ((const float4*)hrow)[k0 * 4 + u];
                hv[u*4+0] = x.x; hv[u*4+1] = x.y; hv[u*4+2] = x.z; hv[u*4+3] = x.w;
            }
            #pragma unroll
            for (int cc = 0; cc < 8; ++cc) {
                const int c = wu * 8 + cc;
                const float* wq  = Wq + c * 64 + k0 * 16;   // wave-uniform -> s_load
                const float* wk  = Wk + c * 64 + k0 * 16;
                const float* wvp = Wv + c * 64 + k0 * 16;
                #pragma unroll
                for (int k = 0; k < 16; ++k) {
                    accQ[cc] = fmaf(hv[k], wq[k],  accQ[cc]);
                    accK[cc] = fmaf(hv[k], wk[k],  accK[cc]);
                    accV[cc] = fmaf(hv[k], wvp[k], accV[cc]);
                }
            }
        }
        const int go = ((wu ^ (lane & 7)) << 3);
        float* kp = &shK[lane * 64 + go];
        *(float4*)(kp)     = make_float4(accK[0], accK[1], accK[2], accK[3]);
        *(float4*)(kp + 4) = make_float4(accK[4], accK[5], accK[6], accK[7]);
        float* vp = &shV[lane * 64 + go];
        *(float4*)(vp)     = make_float4(accV[0], accV[1], accV[2], accV[3]);
        *(float4*)(vp + 4) = make_float4(accV[4], accV[5], accV[6], accV[7]);
        if (lane >= joff && lane < joff + 32) {
            const int rl = lane - joff;
            float* qp = &shQ[rl * 64 + ((wu ^ (rl & 7)) << 3)];
            *(float4*)(qp)     = make_float4(accQ[0], accQ[1], accQ[2], accQ[3]);
            *(float4*)(qp + 4) = make_float4(accQ[4], accQ[5], accQ[6], accQ[7]);
        }
    }
    __syncthreads();

    // ---- P1: per-thread Q fragment
    float q[8];
    {
        const float* qp = &shQ[j_local * 64 + ((hh ^ (j_local & 7)) << 3)];
        const float4 a = *(const float4*)qp;
        const float4 c = *(const float4*)(qp + 4);
        q[0]=a.x; q[1]=a.y; q[2]=a.z; q[3]=a.w;
        q[4]=c.x; q[5]=c.y; q[6]=c.z; q[7]=c.w;
    }

    // ---- P2: proj_e (double-buffered e chunks); also issue adj/rel chunk 1
    {
        float pe[8];
        #pragma unroll
        for (int h2 = 0; h2 < 8; ++h2) pe[h2] = bpe[h2];
        ELOAD(E1, 1); ECONS(E0, 0);
        ELOAD(E0, 2); ECONS(E1, 1);
        ELOAD(E1, 3); LOADCH(A1, R1, 1); ECONS(E0, 2);
        ECONS(E1, 3);
        float* p0 = &shPE[t * 8];
        *(float4*)(p0)     = make_float4(pe[0], pe[1], pe[2], pe[3]);
        *(float4*)(p0 + 4) = make_float4(pe[4], pe[5], pe[6], pe[7]);
    }
    __syncthreads();

    // ---- P3: scores + softmax, 4 chunks of 8 i's, loads one chunk ahead
    float den = 0.f;
    float wv[8] = {0.f,0.f,0.f,0.f,0.f,0.f,0.f,0.f};
    const float inv_scale = 0.35355339059327379f;  // 1/sqrt(8)
    COMPCH(A0, R0, 0);
    LOADCH(A0, R0, 2);
    COMPCH(A1, R1, 1);
    LOADCH(A1, R1, 3);
    COMPCH(A0, R0, 2);
    COMPCH(A1, R1, 3);

    den += __shfl_xor(den, 1);
    #pragma unroll
    for (int u = 0; u < 8; ++u) wv[u] += __shfl_xor(wv[u], 1);
    if (half == 0) {
        const float id = 1.f / den;
        float* wp = &shQ[j_local * 64 + ((hh ^ (j_local & 7)) << 3)];  // shQ := wV
        *(float4*)(wp)     = make_float4(wv[0]*id, wv[1]*id, wv[2]*id, wv[3]*id);
        *(float4*)(wp + 4) = make_float4(wv[4]*id, wv[5]*id, wv[6]*id, wv[7]*id);
    }
    __syncthreads();

    // ---- P4: coalesced sc_sp dump (thread t -> sparse row t of this block)
    {
        const float4 a = *(const float4*)&shSC[t * 8];
        const float4 c = *(const float4*)&shSC[t * 8 + 4];
        float* sp = scsp + (size_t)((size_t)b * 1024 + joff * 16 + t) * sstride;
        *(float4*)(sp)     = a;
        *(float4*)(sp + 4) = c;
    }

    // ---- P5: h_out rows. thread = (rl = t>>4, cq = t&15)
    {
        const int rl = t >> 4;
        const int cq = t & 15;
        float acc[4];
        #pragma unroll
        for (int u = 0; u < 4; ++u) acc[u] = bo[cq * 4 + u];
        #pragma unroll
        for (int k0 = 0; k0 < 4; ++k0) {
            float tv[16];
            #pragma unroll
            for (int u = 0; u < 4; ++u) {
                const int c = k0 * 16 + u * 4;
                const float* p = &shQ[rl * 64 + (((c >> 3) ^ (rl & 7)) << 3) + (c & 7)];
                const float4 x = *(const float4*)p;
                tv[u*4+0] = x.x; tv[u*4+1] = x.y; tv[u*4+2] = x.z; tv[u*4+3] = x.w;
            }
            #pragma unroll
            for (int u = 0; u < 4; ++u) {
                const float* wo = Wo + (cq * 4 + u) * 64 + k0 * 16;
                #pragma unroll
                for (int k = 0; k < 16; ++k)
                    acc[u] = fmaf(tv[k], wo[k], acc[u]);
            }
        }
        float* orow = h_out + (size_t)(b * 64 + joff + rl) * 64 + cq * 4;
        *(float4*)orow = make_float4(acc[0], acc[1], acc[2], acc[3]);
    }
}

// Fold: e_out = e @ Woe^T + sc_sp @ M2^T + bc,  M2 = Woe@Wap [64x8],
// bc[c] = boe[c] + sum_k bap[k]*Woe[c,k].  prep_kernel computes M2||bc into ws.
__global__ void prep_kernel(const float* __restrict__ Wap, const float* __restrict__ bap,
                            const float* __restrict__ Woe, const float* __restrict__ boe,
                            float* __restrict__ M2)
{
    const int t = blockIdx.x * 64 + threadIdx.x;   // 576 threads total
    if (t < 512) {
        const int c = t >> 3, hq = t & 7;
        float s = 0.f;
        #pragma unroll 8
        for (int k = 0; k < 64; ++k) s = fmaf(Woe[c * 64 + k], Wap[k * 8 + hq], s);
        M2[t] = s;
    } else if (t < 576) {
        const int c = t - 512;
        float s = boe[c];
        #pragma unroll 8
        for (int k = 0; k < 64; ++k) s = fmaf(bap[k], Woe[c * 64 + k], s);
        M2[512 + c] = s;
    }
}

// eout: LDS-tiled, 64 rows/block, wave = 16-col group, lane = row. VGPR ~60.
template<int M2G>
__global__ __launch_bounds__(256, 4) void eout_kernel(
    const float* __restrict__ e,
    const float* __restrict__ scsp,
    const float* __restrict__ Wap, const float* __restrict__ bap,
    const float* __restrict__ Woe, const float* __restrict__ boe,
    const float* __restrict__ M2g,     // [512] M2 then [64] bc (when M2G)
    float* __restrict__ e_out, int sstride)
{
    __shared__ float shE[64 * 64];   // swizzled: chunk cc of row r at r*64 + ((cc^(r&15))<<2)
    __shared__ float shS[64 * 8];
    __shared__ float shM[576];       // fallback M2 (+bc) when !M2G

    const int t    = threadIdx.x;
    const int base = blockIdx.x * 64;

    {   // coop e-tile load: thread = (r = t>>2, qq = t&3), 4 float4
        const int r = t >> 2, qq = t & 3;
        const float* ep = e + (size_t)(base + r) * 64 + qq * 16;
        #pragma unroll
        for (int u = 0; u < 4; ++u) {
            const float4 x = ((const float4*)ep)[u];
            const int cc = qq * 4 + u;
            *(float4*)&shE[r * 64 + ((cc ^ (r & 15)) << 2)] = x;
        }
    }
    if (t < 128) {
        const int r = t >> 1, pp = t & 1;
        *(float4*)&shS[r * 8 + pp * 4] =
            *(const float4*)(scsp + (size_t)(base + r) * sstride + pp * 4);
    }
    if (!M2G) {
        #pragma unroll
        for (int z = 0; z < 2; ++z) {
            const int idx = t * 2 + z;
            const int c = idx >> 3, hq = idx & 7;
            float s = 0.f;
            for (int k = 0; k < 64; ++k) s = fmaf(Woe[c * 64 + k], Wap[k * 8 + hq], s);
            shM[idx] = s;
        }
        if (t < 64) {
            float s = boe[t];
            for (int k = 0; k < 64; ++k) s = fmaf(bap[k], Woe[t * 64 + k], s);
            shM[512 + t] = s;
        }
    }
    __syncthreads();

    const int w = __builtin_amdgcn_readfirstlane(t >> 6);  // col group, uniform
    const int r = t & 63;

    float sc[8];
    {
        const float4 a  = *(const float4*)&shS[r * 8];
        const float4 c4 = *(const float4*)&shS[r * 8 + 4];
        sc[0]=a.x; sc[1]=a.y; sc[2]=a.z; sc[3]=a.w;
        sc[4]=c4.x; sc[5]=c4.y; sc[6]=c4.z; sc[7]=c4.w;
    }
    float acc[16];
    #pragma unroll
    for (int u = 0; u < 16; ++u) {
        const int c = w * 16 + u;                       // wave-uniform
        float s = M2G ? M2g[512 + c] : shM[512 + c];
        #pragma unroll
        for (int hq = 0; hq < 8; ++hq)
            s = fmaf(sc[hq], (M2G ? M2g[c * 8 + hq] : shM[c * 8 + hq]), s);
        acc[u] = s;
    }
    #pragma unroll
    for (int k0 = 0; k0 < 4; ++k0) {
        float ev[16];
        #pragma unroll
        for (int v = 0; v < 4; ++v) {
            const int cc = k0 * 4 + v;
            const float4 x = *(const float4*)&shE[r * 64 + ((cc ^ (r & 15)) << 2)];
            ev[v*4+0] = x.x; ev[v*4+1] = x.y; ev[v*4+2] = x.z; ev[v*4+3] = x.w;
        }
        #pragma unroll
        for (int u = 0; u < 16; ++u) {
            const float* wr = Woe + (w * 16 + u) * 64 + k0 * 16;  // wave-uniform -> s_load
            #pragma unroll
            for (int k = 0; k < 16; ++k)
                acc[u] = fmaf(ev[k], wr[k], acc[u]);
        }
    }
    float* orow = e_out + (size_t)(base + r) * 64 + w * 16;
    #pragma unroll
    for (int u = 0; u < 4; ++u)
        *(float4*)&orow[u * 4] =
            make_float4(acc[u*4+0], acc[u*4+1], acc[u*4+2], acc[u*4+3]);
}

extern "C" void kernel_launch(void* const* d_in, const int* in_sizes, int n_in,
                              void* d_out, int out_size, void* d_ws, size_t ws_size,
                              hipStream_t stream) {
    const float* h    = (const float*)d_in[0];
    const float* e    = (const float*)d_in[1];
    const float* adj2 = (const float*)d_in[2];
    const float* rel  = (const float*)d_in[3];
    const float* Wq   = (const float*)d_in[4];  const float* bq  = (const float*)d_in[5];
    const float* Wk   = (const float*)d_in[6];  const float* bk  = (const float*)d_in[7];
    const float* Wv   = (const float*)d_in[8];  const float* bv  = (const float*)d_in[9];
    const float* Wpe  = (const float*)d_in[10]; const float* bpe = (const float*)d_in[11];
    const float* Wap  = (const float*)d_in[12]; const float* bap = (const float*)d_in[13];
    const float* Wo   = (const float*)d_in[14]; const float* bo  = (const float*)d_in[15];
    const float* Woe  = (const float*)d_in[16]; const float* boe = (const float*)d_in[17];

    float* out  = (float*)d_out;
    float* hout = out;                    // [16384*64]
    float* eout = out + 16384 * 64;       // [262144*64]
    float* ws   = (float*)d_ws;

    const size_t needSc = (size_t)262144 * 8 * sizeof(float);   // 8 MB
    float* scsp; int sstride; float* M2g = nullptr;
    if (ws_size >= needSc + 4096)      { scsp = ws;   sstride = 8;  M2g = ws + 2097152; }
    else if (ws_size >= 4096)          { scsp = eout; sstride = 64; M2g = ws; }
    else                               { scsp = eout; sstride = 64; }

    if (M2g)
        prep_kernel<<<dim3(9), dim3(64), 0, stream>>>(Wap, bap, Woe, boe, M2g);

    attn_kernel<<<dim3(512), dim3(512), 0, stream>>>(
        h, e, adj2, rel, Wq, bq, Wk, bk, Wv, bv, Wpe, bpe, Wo, bo, hout, scsp, sstride);

    if (M2g)
        eout_kernel<1><<<dim3(4096), dim3(256), 0, stream>>>(
            e, scsp, Wap, bap, Woe, boe, M2g, eout, sstride);
    else
        eout_kernel<0><<<dim3(4096), dim3(256), 0, stream>>>(
            e, scsp, Wap, bap, Woe, boe, nullptr, eout, sstride);
}

// Round 4
// 163.941 us; speedup vs baseline: 2.0475x; 1.6890x over previous
//
#include <hip/hip_runtime.h>

// Geometry: G=256 graphs x 64 nodes, H=8 heads x D=8, IN_DIM=EDGE_DIM=64
// EF = 1048576 full edges, ES = 262144 sparse edges.
// edge f = b*4096 + i*64 + j (src=i, dst=j); sparse s = b*1024 + j*16 + k, i=(j+1+k)&63.
//
// NOTE launch_bounds: (X, >=4) makes the allocator cap at 64 VGPR and SPILL
// (r2/r3 evidence: WRITE_SIZE 283MB vs 12MB ideal). Use min-waves=2 -> cap 256.

__global__ __launch_bounds__(512, 2) void attn_kernel(
    const float* __restrict__ h,
    const float* __restrict__ e,
    const float* __restrict__ adj2,
    const float* __restrict__ rel,
    const float* __restrict__ Wq, const float* __restrict__ bq,
    const float* __restrict__ Wk, const float* __restrict__ bk,
    const float* __restrict__ Wv, const float* __restrict__ bv,
    const float* __restrict__ Wpe, const float* __restrict__ bpe,
    const float* __restrict__ Wo, const float* __restrict__ bo,
    float* __restrict__ h_out,
    float* __restrict__ scsp, int sstride)
{
    __shared__ float shK[64 * 64];   // swizzled [r][c] at r*64 + (((c>>3)^(r&7))<<3)+(c&7)
    __shared__ float shV[64 * 64];
    __shared__ float shQ[32 * 64];   // this block's j rows; reused for wV
    __shared__ float shPE[512 * 8];
    __shared__ float shSC[512 * 8];

    const int b2   = blockIdx.x;
    const int b    = b2 >> 1;
    const int joff = (b2 & 1) << 5;          // 0 or 32
    const int t    = threadIdx.x;
    const int lane = t & 63;
    const int wu   = __builtin_amdgcn_readfirstlane(t >> 6);

    // ---- P0: Q,K,V = h @ W^T + b for all 64 rows of graph b
    {
        const float* hrow = h + (size_t)(b * 64 + lane) * 64;
        float accQ[8], accK[8], accV[8];
        #pragma unroll
        for (int cc = 0; cc < 8; ++cc) {
            const int c = wu * 8 + cc;
            accQ[cc] = bq[c]; accK[cc] = bk[c]; accV[cc] = bv[c];
        }
        #pragma unroll
        for (int k0 = 0; k0 < 4; ++k0) {
            float hv[16];
            #pragma unroll
            for (int u = 0; u < 4; ++u) {
                const float4 x = ((const float4*)hrow)[k0 * 4 + u];
                hv[u*4+0] = x.x; hv[u*4+1] = x.y; hv[u*4+2] = x.z; hv[u*4+3] = x.w;
            }
            #pragma unroll
            for (int cc = 0; cc < 8; ++cc) {
                const int c = wu * 8 + cc;
                const float* wq  = Wq + c * 64 + k0 * 16;   // wave-uniform -> s_load
                const float* wk  = Wk + c * 64 + k0 * 16;
                const float* wvp = Wv + c * 64 + k0 * 16;
                #pragma unroll
                for (int k = 0; k < 16; ++k) {
                    accQ[cc] = fmaf(hv[k], wq[k],  accQ[cc]);
                    accK[cc] = fmaf(hv[k], wk[k],  accK[cc]);
                    accV[cc] = fmaf(hv[k], wvp[k], accV[cc]);
                }
            }
        }
        const int go = ((wu ^ (lane & 7)) << 3);  // swizzled col-group offset
        float* kp = &shK[lane * 64 + go];
        *(float4*)(kp)     = make_float4(accK[0], accK[1], accK[2], accK[3]);
        *(float4*)(kp + 4) = make_float4(accK[4], accK[5], accK[6], accK[7]);
        float* vp = &shV[lane * 64 + go];
        *(float4*)(vp)     = make_float4(accV[0], accV[1], accV[2], accV[3]);
        *(float4*)(vp + 4) = make_float4(accV[4], accV[5], accV[6], accV[7]);
        if (lane >= joff && lane < joff + 32) {
            const int rl = lane - joff;
            float* qp = &shQ[rl * 64 + ((wu ^ (rl & 7)) << 3)];
            *(float4*)(qp)     = make_float4(accQ[0], accQ[1], accQ[2], accQ[3]);
            *(float4*)(qp + 4) = make_float4(accQ[4], accQ[5], accQ[6], accQ[7]);
        }
    }
    __syncthreads();

    // ---- P1: per-thread Q fragment. thread = (j_local, hh, half)
    const int j_local = t >> 4;
    const int hh      = (t >> 1) & 7;
    const int half    = t & 1;
    const int j       = joff + j_local;
    float q[8];
    {
        const float* qp = &shQ[j_local * 64 + ((hh ^ (j_local & 7)) << 3)];
        const float4 a = *(const float4*)qp;
        const float4 c = *(const float4*)(qp + 4);
        q[0]=a.x; q[1]=a.y; q[2]=a.z; q[3]=a.w;
        q[4]=c.x; q[5]=c.y; q[6]=c.z; q[7]=c.w;
    }

    // ---- P2: proj_e for this block's 512 sparse rows (one per thread)
    {
        const float* erow = e + ((size_t)b * 1024 + joff * 16 + t) * 64;
        float acc[8];
        #pragma unroll
        for (int h2 = 0; h2 < 8; ++h2) acc[h2] = bpe[h2];
        #pragma unroll
        for (int k0 = 0; k0 < 4; ++k0) {
            float ev[16];
            #pragma unroll
            for (int u = 0; u < 4; ++u) {
                const float4 x = ((const float4*)erow)[k0 * 4 + u];
                ev[u*4+0] = x.x; ev[u*4+1] = x.y; ev[u*4+2] = x.z; ev[u*4+3] = x.w;
            }
            #pragma unroll
            for (int h2 = 0; h2 < 8; ++h2) {
                const float* wp = Wpe + h2 * 64 + k0 * 16;  // block-uniform -> s_load
                #pragma unroll
                for (int k = 0; k < 16; ++k)
                    acc[h2] = fmaf(ev[k], wp[k], acc[h2]);
            }
        }
        float* p0 = &shPE[t * 8];
        *(float4*)(p0)     = make_float4(acc[0], acc[1], acc[2], acc[3]);
        *(float4*)(p0 + 4) = make_float4(acc[4], acc[5], acc[6], acc[7]);
    }
    __syncthreads();

    // ---- P3: scores + softmax accumulation over this thread's 32 i's
    float den = 0.f;
    float wv[8] = {0.f,0.f,0.f,0.f,0.f,0.f,0.f,0.f};
    const float* adjB = adj2 + (size_t)b * 4096;
    const float* relB = rel  + (size_t)b * 4096 * 8;
    const float inv_scale = 0.35355339059327379f;  // 1/sqrt(8)
    #pragma unroll 4
    for (int it = 0; it < 32; ++it) {
        const int i  = (half << 5) + it;
        const int kb = i * 64 + ((hh ^ (i & 7)) << 3);
        const float4 kA = *(const float4*)&shK[kb];
        const float4 kB = *(const float4*)&shK[kb + 4];
        float s;
        s = kA.x * q[0];
        s = fmaf(kA.y, q[1], s); s = fmaf(kA.z, q[2], s); s = fmaf(kA.w, q[3], s);
        s = fmaf(kB.x, q[4], s); s = fmaf(kB.y, q[5], s); s = fmaf(kB.z, q[6], s);
        s = fmaf(kB.w, q[7], s);
        const int eidx = i * 64 + j;
        const float a2 = adjB[eidx];
        const float rp = relB[eidx * 8 + hh];
        s = fmaf(s * inv_scale, a2, rp);          // score (pre proj_e, unclipped)
        const int kidx = (i - j - 1) & 63;
        if (kidx < 16) {                          // sparse edge (i -> j)
            const int sl = j_local * 16 + kidx;
            shSC[sl * 8 + hh] = s;                // sc_sp for e_out kernel
            s += shPE[sl * 8 + hh];               // softmax sees sc_sp + proj_e
        }
        s = fminf(fmaxf(s, -5.f), 5.f);
        const float ex = __expf(s);
        den += ex;
        const float4 vA = *(const float4*)&shV[kb];
        const float4 vB = *(const float4*)&shV[kb + 4];
        wv[0] = fmaf(ex, vA.x, wv[0]); wv[1] = fmaf(ex, vA.y, wv[1]);
        wv[2] = fmaf(ex, vA.z, wv[2]); wv[3] = fmaf(ex, vA.w, wv[3]);
        wv[4] = fmaf(ex, vB.x, wv[4]); wv[5] = fmaf(ex, vB.y, wv[5]);
        wv[6] = fmaf(ex, vB.z, wv[6]); wv[7] = fmaf(ex, vB.w, wv[7]);
    }
    // reduce the two i-halves (lane pair differs in bit 0)
    den += __shfl_xor(den, 1);
    #pragma unroll
    for (int u = 0; u < 8; ++u) wv[u] += __shfl_xor(wv[u], 1);
    if (half == 0) {
        const float id = 1.f / den;
        float* wp = &shQ[j_local * 64 + ((hh ^ (j_local & 7)) << 3)];  // shQ := wV
        *(float4*)(wp)     = make_float4(wv[0]*id, wv[1]*id, wv[2]*id, wv[3]*id);
        *(float4*)(wp + 4) = make_float4(wv[4]*id, wv[5]*id, wv[6]*id, wv[7]*id);
    }
    __syncthreads();

    // ---- P4: coalesced sc_sp dump (thread t -> sparse row t of this block)
    {
        const float4 a = *(const float4*)&shSC[t * 8];
        const float4 c = *(const float4*)&shSC[t * 8 + 4];
        float* sp = scsp + (size_t)((size_t)b * 1024 + joff * 16 + t) * sstride;
        *(float4*)(sp)     = a;
        *(float4*)(sp + 4) = c;
    }

    // ---- P5: h_out rows = this block's 32 j's. thread = (rl = t>>4, cq = t&15)
    {
        const int rl = t >> 4;
        const int cq = t & 15;
        float acc[4];
        #pragma unroll
        for (int u = 0; u < 4; ++u) acc[u] = bo[cq * 4 + u];
        #pragma unroll
        for (int k0 = 0; k0 < 4; ++k0) {
            float tv[16];
            #pragma unroll
            for (int u = 0; u < 4; ++u) {
                const int c = k0 * 16 + u * 4;
                const float* p = &shQ[rl * 64 + (((c >> 3) ^ (rl & 7)) << 3) + (c & 7)];
                const float4 x = *(const float4*)p;
                tv[u*4+0] = x.x; tv[u*4+1] = x.y; tv[u*4+2] = x.z; tv[u*4+3] = x.w;
            }
            #pragma unroll
            for (int u = 0; u < 4; ++u) {
                const float* wo = Wo + (cq * 4 + u) * 64 + k0 * 16;
                #pragma unroll
                for (int k = 0; k < 16; ++k)
                    acc[u] = fmaf(tv[k], wo[k], acc[u]);
            }
        }
        float* orow = h_out + (size_t)(b * 64 + joff + rl) * 64 + cq * 4;
        *(float4*)orow = make_float4(acc[0], acc[1], acc[2], acc[3]);
    }
}

// Fold: e_out = e @ Woe^T + sc_sp @ M2^T + bc,  M2 = Woe@Wap [64x8],
// bc[c] = boe[c] + sum_k bap[k]*Woe[c,k].  prep_kernel computes M2||bc into ws.
__global__ void prep_kernel(const float* __restrict__ Wap, const float* __restrict__ bap,
                            const float* __restrict__ Woe, const float* __restrict__ boe,
                            float* __restrict__ M2)
{
    const int t = blockIdx.x * 64 + threadIdx.x;   // 576 threads total
    if (t < 512) {
        const int c = t >> 3, hq = t & 7;
        float s = 0.f;
        #pragma unroll 8
        for (int k = 0; k < 64; ++k) s = fmaf(Woe[c * 64 + k], Wap[k * 8 + hq], s);
        M2[t] = s;
    } else if (t < 576) {
        const int c = t - 512;
        float s = boe[c];
        #pragma unroll 8
        for (int k = 0; k < 64; ++k) s = fmaf(bap[k], Woe[c * 64 + k], s);
        M2[512 + c] = s;
    }
}

// eout: LDS-tiled, 64 rows/block, wave = 16-col group, lane = row.
template<int M2G>
__global__ __launch_bounds__(256, 2) void eout_kernel(
    const float* __restrict__ e,
    const float* __restrict__ scsp,
    const float* __restrict__ Wap, const float* __restrict__ bap,
    const float* __restrict__ Woe, const float* __restrict__ boe,
    const float* __restrict__ M2g,     // [512] M2 then [64] bc (when M2G)
    float* __restrict__ e_out, int sstride)
{
    __shared__ float shE[64 * 64];   // swizzled: chunk cc of row r at r*64 + ((cc^(r&15))<<2)
    __shared__ float shS[64 * 8];
    __shared__ float shM[576];       // fallback M2 (+bc) when !M2G

    const int t    = threadIdx.x;
    const int base = blockIdx.x * 64;

    {   // coop e-tile load: thread = (r = t>>2, qq = t&3), 4 float4
        const int r = t >> 2, qq = t & 3;
        const float* ep = e + (size_t)(base + r) * 64 + qq * 16;
        #pragma unroll
        for (int u = 0; u < 4; ++u) {
            const float4 x = ((const float4*)ep)[u];
            const int cc = qq * 4 + u;
            *(float4*)&shE[r * 64 + ((cc ^ (r & 15)) << 2)] = x;
        }
    }
    if (t < 128) {
        const int r = t >> 1, pp = t & 1;
        *(float4*)&shS[r * 8 + pp * 4] =
            *(const float4*)(scsp + (size_t)(base + r) * sstride + pp * 4);
    }
    if (!M2G) {
        #pragma unroll
        for (int z = 0; z < 2; ++z) {
            const int idx = t * 2 + z;
            const int c = idx >> 3, hq = idx & 7;
            float s = 0.f;
            for (int k = 0; k < 64; ++k) s = fmaf(Woe[c * 64 + k], Wap[k * 8 + hq], s);
            shM[idx] = s;
        }
        if (t < 64) {
            float s = boe[t];
            for (int k = 0; k < 64; ++k) s = fmaf(bap[k], Woe[t * 64 + k], s);
            shM[512 + t] = s;
        }
    }
    __syncthreads();

    const int w = __builtin_amdgcn_readfirstlane(t >> 6);  // col group, uniform
    const int r = t & 63;

    float sc[8];
    {
        const float4 a  = *(const float4*)&shS[r * 8];
        const float4 c4 = *(const float4*)&shS[r * 8 + 4];
        sc[0]=a.x; sc[1]=a.y; sc[2]=a.z; sc[3]=a.w;
        sc[4]=c4.x; sc[5]=c4.y; sc[6]=c4.z; sc[7]=c4.w;
    }
    float acc[16];
    #pragma unroll
    for (int u = 0; u < 16; ++u) {
        const int c = w * 16 + u;                       // wave-uniform
        float s = M2G ? M2g[512 + c] : shM[512 + c];
        #pragma unroll
        for (int hq = 0; hq < 8; ++hq)
            s = fmaf(sc[hq], (M2G ? M2g[c * 8 + hq] : shM[c * 8 + hq]), s);
        acc[u] = s;
    }
    #pragma unroll
    for (int k0 = 0; k0 < 4; ++k0) {
        float ev[16];
        #pragma unroll
        for (int v = 0; v < 4; ++v) {
            const int cc = k0 * 4 + v;
            const float4 x = *(const float4*)&shE[r * 64 + ((cc ^ (r & 15)) << 2)];
            ev[v*4+0] = x.x; ev[v*4+1] = x.y; ev[v*4+2] = x.z; ev[v*4+3] = x.w;
        }
        #pragma unroll
        for (int u = 0; u < 16; ++u) {
            const float* wr = Woe + (w * 16 + u) * 64 + k0 * 16;  // wave-uniform -> s_load
            #pragma unroll
            for (int k = 0; k < 16; ++k)
                acc[u] = fmaf(ev[k], wr[k], acc[u]);
        }
    }
    float* orow = e_out + (size_t)(base + r) * 64 + w * 16;
    #pragma unroll
    for (int u = 0; u < 4; ++u)
        *(float4*)&orow[u * 4] =
            make_float4(acc[u*4+0], acc[u*4+1], acc[u*4+2], acc[u*4+3]);
}

extern "C" void kernel_launch(void* const* d_in, const int* in_sizes, int n_in,
                              void* d_out, int out_size, void* d_ws, size_t ws_size,
                              hipStream_t stream) {
    const float* h    = (const float*)d_in[0];
    const float* e    = (const float*)d_in[1];
    const float* adj2 = (const float*)d_in[2];
    const float* rel  = (const float*)d_in[3];
    const float* Wq   = (const float*)d_in[4];  const float* bq  = (const float*)d_in[5];
    const float* Wk   = (const float*)d_in[6];  const float* bk  = (const float*)d_in[7];
    const float* Wv   = (const float*)d_in[8];  const float* bv  = (const float*)d_in[9];
    const float* Wpe  = (const float*)d_in[10]; const float* bpe = (const float*)d_in[11];
    const float* Wap  = (const float*)d_in[12]; const float* bap = (const float*)d_in[13];
    const float* Wo   = (const float*)d_in[14]; const float* bo  = (const float*)d_in[15];
    const float* Woe  = (const float*)d_in[16]; const float* boe = (const float*)d_in[17];

    float* out  = (float*)d_out;
    float* hout = out;                    // [16384*64]
    float* eout = out + 16384 * 64;       // [262144*64]
    float* ws   = (float*)d_ws;

    const size_t needSc = (size_t)262144 * 8 * sizeof(float);   // 8 MB
    float* scsp; int sstride; float* M2g = nullptr;
    if (ws_size >= needSc + 4096)      { scsp = ws;   sstride = 8;  M2g = ws + 2097152; }
    else if (ws_size >= 4096)          { scsp = eout; sstride = 64; M2g = ws; }
    else                               { scsp = eout; sstride = 64; }

    if (M2g)
        prep_kernel<<<dim3(9), dim3(64), 0, stream>>>(Wap, bap, Woe, boe, M2g);

    attn_kernel<<<dim3(512), dim3(512), 0, stream>>>(
        h, e, adj2, rel, Wq, bq, Wk, bk, Wv, bv, Wpe, bpe, Wo, bo, hout, scsp, sstride);

    if (M2g)
        eout_kernel<1><<<dim3(4096), dim3(256), 0, stream>>>(
            e, scsp, Wap, bap, Woe, boe, M2g, eout, sstride);
    else
        eout_kernel<0><<<dim3(4096), dim3(256), 0, stream>>>(
            e, scsp, Wap, bap, Woe, boe, nullptr, eout, sstride);
}